// Round 1
// baseline (122.481 us; speedup 1.0000x reference)
//
#include <hip/hip_runtime.h>
#include <stdint.h>

#define NPTS 8192
#define TILE 2048
#define NTILES (NPTS / TILE)

__device__ __forceinline__ uint32_t umin32(uint32_t a, uint32_t b) { return a < b ? a : b; }
__device__ __forceinline__ uint32_t umax32(uint32_t a, uint32_t b) { return a > b ? a : b; }

// Insert key into sorted top-3 (k0 <= k1 <= k2), unsigned keys. 5 VALU ops.
__device__ __forceinline__ void ins3(uint32_t key, uint32_t& k0, uint32_t& k1, uint32_t& k2) {
    uint32_t a = umin32(k0, key);
    uint32_t b = umax32(k0, key);
    k0 = a;
    uint32_t c = umin32(k1, b);
    uint32_t d = umax32(k1, b);
    k1 = c;
    k2 = umin32(k2, d);
}

__global__ __launch_bounds__(1024) void knnreg_kernel(
    const float* __restrict__ xyz,   // [B, N, 3]
    const float* __restrict__ rot,   // [B, N, 4]
    const float* __restrict__ sc,    // [B, N, 3]
    const float* __restrict__ col,   // [B, N, 45]
    const float* __restrict__ opac,  // [B, N, 1]
    float* __restrict__ out)         // [1]
{
    __shared__ __align__(16) float xs[TILE];
    __shared__ __align__(16) float ys[TILE];
    __shared__ __align__(16) float zs[TILE];
    __shared__ float blockAcc;

    const int tid  = threadIdx.x;
    const int lane = tid & 63;
    const int wv   = tid >> 6;
    const int bb   = blockIdx.x >> 7;   // 128 blocks per batch
    const int blk  = blockIdx.x & 127;
    const float* xb = xyz + (size_t)bb * NPTS * 3;
    const int ibase = blk * 64 + wv * 4;  // 4 points per wave, 64 per block

    if (tid == 0) blockAcc = 0.0f;

    // Query points for this wave (same for all lanes — broadcast loads).
    float xi[4], yi[4], zi[4];
#pragma unroll
    for (int p = 0; p < 4; ++p) {
        xi[p] = xb[(ibase + p) * 3 + 0];
        yi[p] = xb[(ibase + p) * 3 + 1];
        zi[p] = xb[(ibase + p) * 3 + 2];
    }

    // Packed keys: high 19 bits = fp32 bits of squared distance (>=0, so
    // unsigned-monotonic), low 13 bits = neighbor index. Self (d=0) wins
    // naturally, matching knn_points(x,x) including self.
    uint32_t k0[4], k1[4], k2[4];
#pragma unroll
    for (int p = 0; p < 4; ++p) { k0[p] = 0xFFFFFFFFu; k1[p] = 0xFFFFFFFFu; k2[p] = 0xFFFFFFFFu; }

    for (int T = 0; T < NTILES; ++T) {
        __syncthreads();  // protect LDS from previous tile's readers
        // Stage tile of xyz into SoA LDS (coalesced global reads).
#pragma unroll
        for (int r = 0; r < (TILE * 3) / 1024; ++r) {
            int e = r * 1024 + tid;
            float v = xb[T * TILE * 3 + e];
            int n = e / 3;
            int c = e - n * 3;
            if (c == 0) xs[n] = v; else if (c == 1) ys[n] = v; else zs[n] = v;
        }
        __syncthreads();

        for (int it = 0; it < TILE / 256; ++it) {
            int jl = it * 256 + lane * 4;
            float4 X = *(const float4*)&xs[jl];
            float4 Y = *(const float4*)&ys[jl];
            float4 Z = *(const float4*)&zs[jl];
            uint32_t jg = (uint32_t)(T * TILE + jl);
            const float* Xp = (const float*)&X;
            const float* Yp = (const float*)&Y;
            const float* Zp = (const float*)&Z;
#pragma unroll
            for (int p = 0; p < 4; ++p) {
                float xp = xi[p], yp = yi[p], zp = zi[p];
#pragma unroll
                for (int u = 0; u < 4; ++u) {
                    float dx = Xp[u] - xp;
                    float dy = Yp[u] - yp;
                    float dz = Zp[u] - zp;
                    float d  = fmaf(dz, dz, fmaf(dy, dy, dx * dx));
                    uint32_t key = (__float_as_uint(d) & 0xFFFFE000u) | (jg + (uint32_t)u);
                    ins3(key, k0[p], k1[p], k2[p]);
                }
            }
        }
    }

    // Merge per-lane top-3 across the wave, then gather attributes + std.
    float acc = 0.0f;
    const size_t abase = (size_t)bb * NPTS;
    for (int p = 0; p < 4; ++p) {
        uint32_t K0 = k0[p], K1 = k1[p], K2 = k2[p];
#pragma unroll
        for (int m = 1; m < 64; m <<= 1) {
            uint32_t r0 = (uint32_t)__shfl_xor((int)K0, m);
            uint32_t r1 = (uint32_t)__shfl_xor((int)K1, m);
            uint32_t r2 = (uint32_t)__shfl_xor((int)K2, m);
            ins3(r0, K0, K1, K2);
            ins3(r1, K0, K1, K2);
            ins3(r2, K0, K1, K2);
        }
        int j0 = (int)(K0 & 8191u);
        int j1 = (int)(K1 & 8191u);
        int j2 = (int)(K2 & 8191u);

        // Lane c owns one channel: [0,4)=rot, [4,7)=sc, 7=op, [8,53)=col, 53=dist.
        int c = lane;
        const float* basep = nullptr;
        int stridec = 0, ch = 0;
        float w = 0.0f;
        if (c < 4)       { basep = rot  + abase * 4;  stridec = 4;  ch = c;     w = 1.0f / (NPTS * 4.0f  * 2.0f); }
        else if (c < 7)  { basep = sc   + abase * 3;  stridec = 3;  ch = c - 4; w = 1.0f / (NPTS * 3.0f  * 2.0f); }
        else if (c == 7) { basep = opac + abase;      stridec = 1;  ch = 0;     w = 1.0f / (NPTS * 1.0f  * 2.0f); }
        else if (c < 53) { basep = col  + abase * 45; stridec = 45; ch = c - 8; w = 1.0f / (NPTS * 45.0f * 2.0f); }

        if (basep != nullptr) {
            float v0 = basep[(size_t)j0 * stridec + ch];
            float v1 = basep[(size_t)j1 * stridec + ch];
            float v2 = basep[(size_t)j2 * stridec + ch];
            float mn = (v0 + v1 + v2) * (1.0f / 3.0f);
            float e0 = v0 - mn, e1 = v1 - mn, e2 = v2 - mn;
            // unbiased std over K=3: sqrt(sum(sq)/ (K-1))
            float s = sqrtf((e0 * e0 + e1 * e1 + e2 * e2) * 0.5f);
            acc += w * s;
        } else if (c == 53) {
            // dist_sq.mean over [N, K]: recompute exact distances for the 3 picks.
            float xp = xi[p], yp = yi[p], zp = zi[p];
            int js[3] = { j0, j1, j2 };
            float ds = 0.0f;
#pragma unroll
            for (int q = 0; q < 3; ++q) {
                float dx = xb[js[q] * 3 + 0] - xp;
                float dy = xb[js[q] * 3 + 1] - yp;
                float dz = xb[js[q] * 3 + 2] - zp;
                ds += fmaf(dz, dz, fmaf(dy, dy, dx * dx));
            }
            acc += ds * (1.0f / (NPTS * 3.0f * 2.0f));
        }
    }

    // Wave reduce, then block reduce, then one global atomic per block.
#pragma unroll
    for (int off = 32; off > 0; off >>= 1) acc += __shfl_xor(acc, off);
    if (lane == 0) atomicAdd(&blockAcc, acc);
    __syncthreads();
    if (tid == 0) atomicAdd(out, blockAcc);
}

extern "C" void kernel_launch(void* const* d_in, const int* in_sizes, int n_in,
                              void* d_out, int out_size, void* d_ws, size_t ws_size,
                              hipStream_t stream) {
    const float* xyz  = (const float*)d_in[0];
    const float* rot  = (const float*)d_in[1];
    const float* sc   = (const float*)d_in[2];
    const float* col  = (const float*)d_in[3];
    const float* opac = (const float*)d_in[4];
    float* out = (float*)d_out;

    const int B = in_sizes[0] / (NPTS * 3);  // = 2

    // d_out is re-poisoned to 0xAA before every launch — zero it ourselves.
    hipMemsetAsync(out, 0, sizeof(float), stream);
    knnreg_kernel<<<dim3(B * 128), dim3(1024), 0, stream>>>(xyz, rot, sc, col, opac, out);
}

// Round 2
// 116.517 us; speedup vs baseline: 1.0512x; 1.0512x over previous
//
#include <hip/hip_runtime.h>
#include <stdint.h>

#define NPTS 8192
#define TILE 2048
#define NTILES (NPTS / TILE)
#define P 2                 // query points per wave
#define BLK 512             // threads per block (8 waves)
#define WAVES_PER_BLK (BLK / 64)
#define PTS_PER_BLK (WAVES_PER_BLK * P)   // 16
#define BLKS_PER_BATCH (NPTS / PTS_PER_BLK)  // 512

__device__ __forceinline__ uint32_t umin32(uint32_t a, uint32_t b) { return a < b ? a : b; }
__device__ __forceinline__ uint32_t umax32(uint32_t a, uint32_t b) { return a > b ? a : b; }

// Insert key into sorted top-3 (k0 <= k1 <= k2), unsigned keys. 5 VALU ops.
__device__ __forceinline__ void ins3(uint32_t key, uint32_t& k0, uint32_t& k1, uint32_t& k2) {
    uint32_t a = umin32(k0, key);
    uint32_t b = umax32(k0, key);
    k0 = a;
    uint32_t c = umin32(k1, b);
    uint32_t d = umax32(k1, b);
    k1 = c;
    k2 = umin32(k2, d);
}

__global__ __launch_bounds__(BLK, 8) void knnreg_kernel(
    const float* __restrict__ xyz,   // [B, N, 3]
    const float* __restrict__ rot,   // [B, N, 4]
    const float* __restrict__ sc,    // [B, N, 3]
    const float* __restrict__ col,   // [B, N, 45]
    const float* __restrict__ opac,  // [B, N, 1]
    float* __restrict__ out,         // [1]
    float inv_nb)                    // 1 / (NPTS * B)
{
    __shared__ __align__(16) float xs[TILE];
    __shared__ __align__(16) float ys[TILE];
    __shared__ __align__(16) float zs[TILE];
    __shared__ float blockAcc;

    const int tid  = threadIdx.x;
    const int lane = tid & 63;
    const int wv   = tid >> 6;
    const int bb   = blockIdx.x / BLKS_PER_BATCH;
    const int blk  = blockIdx.x % BLKS_PER_BATCH;
    const float* xb = xyz + (size_t)bb * NPTS * 3;
    const int ibase = blk * PTS_PER_BLK + wv * P;

    if (tid == 0) blockAcc = 0.0f;

    // Query points for this wave (same for all lanes — broadcast loads).
    float xi[P], yi[P], zi[P];
#pragma unroll
    for (int p = 0; p < P; ++p) {
        xi[p] = xb[(ibase + p) * 3 + 0];
        yi[p] = xb[(ibase + p) * 3 + 1];
        zi[p] = xb[(ibase + p) * 3 + 2];
    }

    // Packed keys: high 19 bits = fp32 bits of squared distance (>=0, so
    // unsigned-monotonic), low 13 bits = neighbor index. Self (d=0) wins
    // naturally, matching knn_points(x,x) including self.
    uint32_t k0[P], k1[P], k2[P];
#pragma unroll
    for (int p = 0; p < P; ++p) { k0[p] = 0xFFFFFFFFu; k1[p] = 0xFFFFFFFFu; k2[p] = 0xFFFFFFFFu; }

    for (int T = 0; T < NTILES; ++T) {
        __syncthreads();  // protect LDS from previous tile's readers
        // Stage tile of xyz into SoA LDS: one point per thread per iter,
        // 3 scalar loads (contiguous 12B/thread -> coalesced) + 3 LDS writes.
#pragma unroll
        for (int r = 0; r < TILE / BLK; ++r) {
            int n = r * BLK + tid;
            const float* src = xb + (size_t)(T * TILE + n) * 3;
            xs[n] = src[0];
            ys[n] = src[1];
            zs[n] = src[2];
        }
        __syncthreads();

        for (int it = 0; it < TILE / 256; ++it) {
            int jl = it * 256 + lane * 4;
            float4 X = *(const float4*)&xs[jl];
            float4 Y = *(const float4*)&ys[jl];
            float4 Z = *(const float4*)&zs[jl];
            uint32_t jg = (uint32_t)(T * TILE + jl);

#define DO_CAND(cx, cy, cz, ju)                                              \
            {                                                                \
                _Pragma("unroll")                                            \
                for (int p = 0; p < P; ++p) {                                \
                    float dx = (cx) - xi[p];                                 \
                    float dy = (cy) - yi[p];                                 \
                    float dz = (cz) - zi[p];                                 \
                    float d  = fmaf(dz, dz, fmaf(dy, dy, dx * dx));          \
                    uint32_t key = (__float_as_uint(d) & 0xFFFFE000u) | (ju);\
                    ins3(key, k0[p], k1[p], k2[p]);                          \
                }                                                            \
            }
            DO_CAND(X.x, Y.x, Z.x, jg + 0u)
            DO_CAND(X.y, Y.y, Z.y, jg + 1u)
            DO_CAND(X.z, Y.z, Z.z, jg + 2u)
            DO_CAND(X.w, Y.w, Z.w, jg + 3u)
#undef DO_CAND
        }
    }

    // Merge per-lane top-3 across the wave, then gather attributes + std.
    float acc = 0.0f;
    const size_t abase = (size_t)bb * NPTS;
    for (int p = 0; p < P; ++p) {
        uint32_t K0 = k0[p], K1 = k1[p], K2 = k2[p];
#pragma unroll
        for (int m = 1; m < 64; m <<= 1) {
            uint32_t r0 = (uint32_t)__shfl_xor((int)K0, m);
            uint32_t r1 = (uint32_t)__shfl_xor((int)K1, m);
            uint32_t r2 = (uint32_t)__shfl_xor((int)K2, m);
            ins3(r0, K0, K1, K2);
            ins3(r1, K0, K1, K2);
            ins3(r2, K0, K1, K2);
        }
        int j0 = (int)(K0 & 8191u);
        int j1 = (int)(K1 & 8191u);
        int j2 = (int)(K2 & 8191u);

        // Lane c owns one channel: [0,4)=rot, [4,7)=sc, 7=op, [8,53)=col, 53=dist.
        int c = lane;
        const float* basep = nullptr;
        int stridec = 0, ch = 0;
        float w = 0.0f;
        if (c < 4)       { basep = rot  + abase * 4;  stridec = 4;  ch = c;     w = inv_nb / 4.0f; }
        else if (c < 7)  { basep = sc   + abase * 3;  stridec = 3;  ch = c - 4; w = inv_nb / 3.0f; }
        else if (c == 7) { basep = opac + abase;      stridec = 1;  ch = 0;     w = inv_nb; }
        else if (c < 53) { basep = col  + abase * 45; stridec = 45; ch = c - 8; w = inv_nb / 45.0f; }

        if (basep != nullptr) {
            float v0 = basep[(size_t)j0 * stridec + ch];
            float v1 = basep[(size_t)j1 * stridec + ch];
            float v2 = basep[(size_t)j2 * stridec + ch];
            float mn = (v0 + v1 + v2) * (1.0f / 3.0f);
            float e0 = v0 - mn, e1 = v1 - mn, e2 = v2 - mn;
            // unbiased std over K=3: sqrt(sum(sq) / (K-1))
            float s = sqrtf((e0 * e0 + e1 * e1 + e2 * e2) * 0.5f);
            acc += w * s;
        } else if (c == 53) {
            // dist_sq.mean over [N, K]: recompute exact distances for the 3 picks.
            float xp = xi[p], yp = yi[p], zp = zi[p];
            int js[3] = { j0, j1, j2 };
            float ds = 0.0f;
#pragma unroll
            for (int q = 0; q < 3; ++q) {
                float dx = xb[js[q] * 3 + 0] - xp;
                float dy = xb[js[q] * 3 + 1] - yp;
                float dz = xb[js[q] * 3 + 2] - zp;
                ds += fmaf(dz, dz, fmaf(dy, dy, dx * dx));
            }
            acc += ds * (inv_nb / 3.0f);
        }
    }

    // Wave reduce, then block reduce, then one global atomic per block.
#pragma unroll
    for (int off = 32; off > 0; off >>= 1) acc += __shfl_xor(acc, off);
    if (lane == 0) atomicAdd(&blockAcc, acc);
    __syncthreads();
    if (tid == 0) atomicAdd(out, blockAcc);
}

extern "C" void kernel_launch(void* const* d_in, const int* in_sizes, int n_in,
                              void* d_out, int out_size, void* d_ws, size_t ws_size,
                              hipStream_t stream) {
    const float* xyz  = (const float*)d_in[0];
    const float* rot  = (const float*)d_in[1];
    const float* sc   = (const float*)d_in[2];
    const float* col  = (const float*)d_in[3];
    const float* opac = (const float*)d_in[4];
    float* out = (float*)d_out;

    const int B = in_sizes[0] / (NPTS * 3);  // = 2
    const float inv_nb = 1.0f / ((float)NPTS * (float)B);

    // d_out is re-poisoned to 0xAA before every launch — zero it ourselves.
    hipMemsetAsync(out, 0, sizeof(float), stream);
    knnreg_kernel<<<dim3(B * BLKS_PER_BATCH), dim3(BLK), 0, stream>>>(
        xyz, rot, sc, col, opac, out, inv_nb);
}